// Round 2
// baseline (93.838 us; speedup 1.0000x reference)
//
#include <hip/hip_runtime.h>

#define NROW 4096
#define NDIM 4
#define JS   64          // j-chunks per row
#define JCH  (NROW / JS) // 64 j's per chunk

// Kernel 1: per row r compute q = x*R, k = x*E (4x4 matvecs), then store
// cos(q/2), sin(q/2), cos(k/2), sin(k/2) as 16 floats at pre[r*16..].
__global__ __launch_bounds__(256) void qs_precompute_kernel(
    const float* __restrict__ inp, const float* __restrict__ rot,
    const float* __restrict__ ent, float* __restrict__ pre) {
  int r = blockIdx.x * 256 + threadIdx.x;
  if (r >= NROW) return;
  float4 x = reinterpret_cast<const float4*>(inp)[r];
  float cq[4], sq[4], ck[4], sk[4];
#pragma unroll
  for (int d = 0; d < 4; ++d) {
    float q = x.x * rot[0 * 4 + d] + x.y * rot[1 * 4 + d] +
              x.z * rot[2 * 4 + d] + x.w * rot[3 * 4 + d];
    float k = x.x * ent[0 * 4 + d] + x.y * ent[1 * 4 + d] +
              x.z * ent[2 * 4 + d] + x.w * ent[3 * 4 + d];
    __sincosf(0.5f * q, &sq[d], &cq[d]);
    __sincosf(0.5f * k, &sk[d], &ck[d]);
  }
  float4* p = reinterpret_cast<float4*>(pre + (size_t)r * 16);
  p[0] = make_float4(cq[0], cq[1], cq[2], cq[3]);
  p[1] = make_float4(sq[0], sq[1], sq[2], sq[3]);
  p[2] = make_float4(ck[0], ck[1], ck[2], ck[3]);
  p[3] = make_float4(sk[0], sk[1], sk[2], sk[3]);
}

// Kernel 2: one wave per (row-group of 64, j-chunk of 64). Lane = one row.
// sim = prod_d (cq*ck + sq*sk); e = exp(sim/2) = exp2(sim * log2(e)/2).
// Accumulate denom and e*v per lane over the j-chunk; atomicAdd partials.
__global__ __launch_bounds__(256) void attn_partial_kernel(
    const float* __restrict__ inp, const float* __restrict__ pre,
    float* __restrict__ part) {
  int lane = threadIdx.x & 63;
  int wave = (blockIdx.x * 256 + threadIdx.x) >> 6;  // 0..4095
  int rowgrp = wave >> 6;                            // 0..63
  int jchunk = wave & 63;                            // 0..63
  int row = (rowgrp << 6) + lane;

  const float4* pr = reinterpret_cast<const float4*>(pre + (size_t)row * 16);
  float4 cq = pr[0];
  float4 sq = pr[1];

  float denom = 0.f, a0 = 0.f, a1 = 0.f, a2 = 0.f, a3 = 0.f;
  int jbase = __builtin_amdgcn_readfirstlane(jchunk << 6);  // wave-uniform

#pragma unroll 4
  for (int it = 0; it < JCH; ++it) {
    int j = jbase + it;  // uniform across the wave -> broadcast/scalar loads
    const float4* pj = reinterpret_cast<const float4*>(pre + (size_t)j * 16);
    float4 ck = pj[2];
    float4 sk = pj[3];
    float4 v = reinterpret_cast<const float4*>(inp)[j];
    float t0 = cq.x * ck.x + sq.x * sk.x;
    float t1 = cq.y * ck.y + sq.y * sk.y;
    float t2 = cq.z * ck.z + sq.z * sk.z;
    float t3 = cq.w * ck.w + sq.w * sk.w;
    float sim = fabsf(t0 * t1 * t2 * t3);
    float e = __builtin_amdgcn_exp2f(sim * 0.72134752044448170367f);
    denom += e;
    a0 += e * v.x;
    a1 += e * v.y;
    a2 += e * v.z;
    a3 += e * v.w;
  }

  float* dst = part + (size_t)row * 5;
  atomicAdd(dst + 0, denom);
  atomicAdd(dst + 1, a0);
  atomicAdd(dst + 2, a1);
  atomicAdd(dst + 3, a2);
  atomicAdd(dst + 4, a3);
}

// Kernel 3: out[i][d] = acc[i][d] / denom[i]
__global__ __launch_bounds__(256) void normalize_kernel(
    const float* __restrict__ part, float* __restrict__ out) {
  int t = blockIdx.x * 256 + threadIdx.x;  // 0..16383
  int i = t >> 2;
  int d = t & 3;
  out[t] = part[i * 5 + 1 + d] / part[i * 5];
}

extern "C" void kernel_launch(void* const* d_in, const int* in_sizes, int n_in,
                              void* d_out, int out_size, void* d_ws, size_t ws_size,
                              hipStream_t stream) {
  const float* inp = (const float*)d_in[0];
  const float* rot = (const float*)d_in[1];
  const float* ent = (const float*)d_in[2];
  float* out = (float*)d_out;

  float* part = (float*)d_ws;            // NROW*5 floats (atomic partials)
  float* pre  = part + NROW * 5;         // NROW*16 floats (cos/sin precompute)

  hipMemsetAsync(part, 0, NROW * 5 * sizeof(float), stream);
  qs_precompute_kernel<<<NROW / 256, 256, 0, stream>>>(inp, rot, ent, pre);
  attn_partial_kernel<<<(NROW * JS * 64) / 256 / 64, 256, 0, stream>>>(inp, pre, part);
  normalize_kernel<<<NROW * NDIM / 256, 256, 0, stream>>>(part, out);
}

// Round 3
// 82.409 us; speedup vs baseline: 1.1387x; 1.1387x over previous
//
#include <hip/hip_runtime.h>

#define NROW 4096

// Kernel A: per row r compute q = x*R, k = x*E (4x4 matvecs), then store
// cos(q/2), sin(q/2), cos(k/2), sin(k/2) as 16 floats at pre[r*16..].
__global__ __launch_bounds__(256) void qs_precompute_kernel(
    const float* __restrict__ inp, const float* __restrict__ rot,
    const float* __restrict__ ent, float* __restrict__ pre) {
  int r = blockIdx.x * 256 + threadIdx.x;
  if (r >= NROW) return;
  float4 x = reinterpret_cast<const float4*>(inp)[r];
  float cq[4], sq[4], ck[4], sk[4];
#pragma unroll
  for (int d = 0; d < 4; ++d) {
    float q = x.x * rot[0 * 4 + d] + x.y * rot[1 * 4 + d] +
              x.z * rot[2 * 4 + d] + x.w * rot[3 * 4 + d];
    float k = x.x * ent[0 * 4 + d] + x.y * ent[1 * 4 + d] +
              x.z * ent[2 * 4 + d] + x.w * ent[3 * 4 + d];
    __sincosf(0.5f * q, &sq[d], &cq[d]);
    __sincosf(0.5f * k, &sk[d], &ck[d]);
  }
  float4* p = reinterpret_cast<float4*>(pre + (size_t)r * 16);
  p[0] = make_float4(cq[0], cq[1], cq[2], cq[3]);
  p[1] = make_float4(sq[0], sq[1], sq[2], sq[3]);
  p[2] = make_float4(ck[0], ck[1], ck[2], ck[3]);
  p[3] = make_float4(sk[0], sk[1], sk[2], sk[3]);
}

// Kernel B: 256 blocks x 1024 threads (16 waves). Block owns 16 rows.
// lane&15 -> local row; slice = wave*4 + (lane>>4) -> 64 j's per lane.
// sim = |prod_d (cq*ck + sq*sk)|; e = exp2(sim * log2(e)/2).
// In-wave shfl reduce (xor 16,32) -> LDS cross-wave reduce -> divide -> store.
__global__ __launch_bounds__(1024) void attn_kernel(
    const float* __restrict__ inp, const float* __restrict__ pre,
    float* __restrict__ out) {
  __shared__ float red[16][16][5];  // [wave][local row][denom,a0..a3]
  const int tid = threadIdx.x;
  const int wave = tid >> 6;
  const int lane = tid & 63;
  const int rloc = lane & 15;
  const int row = (blockIdx.x << 4) + rloc;
  const int slice = (wave << 2) + (lane >> 4);  // 0..63
  const int jbase = slice << 6;                 // 64 j's per slice

  const float4* pr = reinterpret_cast<const float4*>(pre + (size_t)row * 16);
  const float4 cq = pr[0];
  const float4 sq = pr[1];

  float denom = 0.f, a0 = 0.f, a1 = 0.f, a2 = 0.f, a3 = 0.f;

#pragma unroll 4
  for (int it = 0; it < 64; ++it) {
    int j = jbase + it;
    const float4* pj = reinterpret_cast<const float4*>(pre + (size_t)j * 16);
    float4 ck = pj[2];
    float4 sk = pj[3];
    float4 v = reinterpret_cast<const float4*>(inp)[j];
    float t0 = fmaf(cq.x, ck.x, sq.x * sk.x);
    float t1 = fmaf(cq.y, ck.y, sq.y * sk.y);
    float t2 = fmaf(cq.z, ck.z, sq.z * sk.z);
    float t3 = fmaf(cq.w, ck.w, sq.w * sk.w);
    float sim = fabsf(t0 * t1 * t2 * t3);
    float e = __builtin_amdgcn_exp2f(sim * 0.72134752044448170367f);
    denom += e;
    a0 = fmaf(e, v.x, a0);
    a1 = fmaf(e, v.y, a1);
    a2 = fmaf(e, v.z, a2);
    a3 = fmaf(e, v.w, a3);
  }

  // In-wave reduce across the 4 slice-groups (lanes l, l^16, l^32, l^48).
#pragma unroll
  for (int off = 16; off <= 32; off <<= 1) {
    denom += __shfl_xor(denom, off, 64);
    a0 += __shfl_xor(a0, off, 64);
    a1 += __shfl_xor(a1, off, 64);
    a2 += __shfl_xor(a2, off, 64);
    a3 += __shfl_xor(a3, off, 64);
  }
  if (lane < 16) {
    red[wave][rloc][0] = denom;
    red[wave][rloc][1] = a0;
    red[wave][rloc][2] = a1;
    red[wave][rloc][3] = a2;
    red[wave][rloc][4] = a3;
  }
  __syncthreads();

  if (wave == 0) {
    const int grp = lane >> 4;  // 0..3
    float d = 0.f, b0 = 0.f, b1 = 0.f, b2 = 0.f, b3 = 0.f;
#pragma unroll
    for (int i = 0; i < 4; ++i) {
      const float* p = red[grp * 4 + i][rloc];
      d += p[0];
      b0 += p[1];
      b1 += p[2];
      b2 += p[3];
      b3 += p[4];
    }
#pragma unroll
    for (int off = 16; off <= 32; off <<= 1) {
      d += __shfl_xor(d, off, 64);
      b0 += __shfl_xor(b0, off, 64);
      b1 += __shfl_xor(b1, off, 64);
      b2 += __shfl_xor(b2, off, 64);
      b3 += __shfl_xor(b3, off, 64);
    }
    if (lane < 16) {
      reinterpret_cast<float4*>(out)[row] =
          make_float4(b0 / d, b1 / d, b2 / d, b3 / d);
    }
  }
}

extern "C" void kernel_launch(void* const* d_in, const int* in_sizes, int n_in,
                              void* d_out, int out_size, void* d_ws, size_t ws_size,
                              hipStream_t stream) {
  const float* inp = (const float*)d_in[0];
  const float* rot = (const float*)d_in[1];
  const float* ent = (const float*)d_in[2];
  float* out = (float*)d_out;
  float* pre = (float*)d_ws;  // NROW*16 floats of cos/sin precompute

  qs_precompute_kernel<<<NROW / 256, 256, 0, stream>>>(inp, rot, ent, pre);
  attn_kernel<<<NROW / 16, 1024, 0, stream>>>(inp, pre, out);
}

// Round 4
// 68.407 us; speedup vs baseline: 1.3718x; 1.2047x over previous
//
#include <hip/hip_runtime.h>

typedef float f2 __attribute__((ext_vector_type(2)));

#define NROW 4096
#define HJ   2048  // j-rows per LDS half

// Single fused kernel. 256 blocks x 1024 threads (16 waves); block owns 16 rows.
// Identity: cos((q-k)/2) = cos(q/2)cos(k/2) + sin(q/2)sin(k/2), and sim in [0,1]
// => softmax needs no max pass. Each block builds the k-side cos/sin table for
// all 4096 j's in LDS (two 2048-row halves, 64 KB), then accumulates.
// Lane layout: rloc = lane&15 (local row), group g = wave*4 + lane>>4 in [0,64);
// group g handles j = it*64 + g (wave's 4 groups read 128 contiguous LDS bytes
// -> conflict-free; v-loads are 64B contiguous per wave).
__global__ __launch_bounds__(1024) void fused_attn_kernel(
    const float* __restrict__ inp, const float* __restrict__ rot,
    const float* __restrict__ ent, float* __restrict__ out) {
  __shared__ float4 kt[2 * HJ];  // 64 KB; entry e = j*2+p: p0 = cos(k/2), p1 = sin(k/2)
  const int tid  = threadIdx.x;
  const int wave = tid >> 6;
  const int lane = tid & 63;
  const int rloc = lane & 15;
  const int row  = (blockIdx.x << 4) + rloc;
  const int g    = (wave << 2) + (lane >> 4);  // 0..63

  const float4* inp4 = reinterpret_cast<const float4*>(inp);

  // q-side for own row (registers)
  float4 xr = inp4[row];
  float qc[4], qs[4];
#pragma unroll
  for (int d = 0; d < 4; ++d) {
    float a = fmaf(xr.x, 0.5f * rot[d],
              fmaf(xr.y, 0.5f * rot[4 + d],
              fmaf(xr.z, 0.5f * rot[8 + d], xr.w * (0.5f * rot[12 + d]))));
    __sincosf(a, &qs[d], &qc[d]);
  }
  f2 qc01 = {qc[0], qc[1]}, qc23 = {qc[2], qc[3]};
  f2 qs01 = {qs[0], qs[1]}, qs23 = {qs[2], qs[3]};

  // piece parity: even tid writes cos-piece, odd writes sin-piece = cos(a - pi/2)
  const float phs = (tid & 1) ? -1.57079632679489662f : 0.f;

  float denom = 0.f, a0 = 0.f, a1 = 0.f, a2 = 0.f, a3 = 0.f;

  for (int h = 0; h < 2; ++h) {
    if (h) __syncthreads();  // all waves done reading kt half h-1
    // build half-table: thread t writes entries e = qq*1024 + t (lane-consecutive)
#pragma unroll
    for (int qq = 0; qq < 4; ++qq) {
      int e = qq * 1024 + tid;  // 0..4095
      int j = e >> 1;           // 0..2047 within half
      float4 xj = inp4[h * HJ + j];
      float4 val;
      val.x = __cosf(fmaf(xj.x, 0.5f * ent[0],
                     fmaf(xj.y, 0.5f * ent[4],
                     fmaf(xj.z, 0.5f * ent[8],
                     fmaf(xj.w, 0.5f * ent[12], phs)))));
      val.y = __cosf(fmaf(xj.x, 0.5f * ent[1],
                     fmaf(xj.y, 0.5f * ent[5],
                     fmaf(xj.z, 0.5f * ent[9],
                     fmaf(xj.w, 0.5f * ent[13], phs)))));
      val.z = __cosf(fmaf(xj.x, 0.5f * ent[2],
                     fmaf(xj.y, 0.5f * ent[6],
                     fmaf(xj.z, 0.5f * ent[10],
                     fmaf(xj.w, 0.5f * ent[14], phs)))));
      val.w = __cosf(fmaf(xj.x, 0.5f * ent[3],
                     fmaf(xj.y, 0.5f * ent[7],
                     fmaf(xj.z, 0.5f * ent[11],
                     fmaf(xj.w, 0.5f * ent[15], phs)))));
      kt[e] = val;
    }
    __syncthreads();

    // accumulate over this half's 2048 j's: 32 per lane
#pragma unroll 4
    for (int it = 0; it < 32; ++it) {
      int jj = (it << 6) + g;
      float4 c4 = kt[jj * 2];
      float4 s4 = kt[jj * 2 + 1];
      float4 v = inp4[h * HJ + jj];
      f2 c01 = {c4.x, c4.y}, c23 = {c4.z, c4.w};
      f2 s01 = {s4.x, s4.y}, s23 = {s4.z, s4.w};
      f2 t01 = c01 * qc01 + s01 * qs01;  // v_pk_mul + v_pk_fma
      f2 t23 = c23 * qc23 + s23 * qs23;
      f2 p = t01 * t23;                  // (t0*t2, t1*t3)
      float m = p.x * p.y;
      float e = __builtin_amdgcn_exp2f(fabsf(m) * 0.72134752044448170367f);
      denom += e;
      a0 = fmaf(e, v.x, a0);
      a1 = fmaf(e, v.y, a1);
      a2 = fmaf(e, v.z, a2);
      a3 = fmaf(e, v.w, a3);
    }
  }

  // in-wave reduce across the 4 slice-groups (lanes l, l^16, l^32, l^48)
#pragma unroll
  for (int off = 16; off <= 32; off <<= 1) {
    denom += __shfl_xor(denom, off, 64);
    a0 += __shfl_xor(a0, off, 64);
    a1 += __shfl_xor(a1, off, 64);
    a2 += __shfl_xor(a2, off, 64);
    a3 += __shfl_xor(a3, off, 64);
  }

  __syncthreads();  // everyone done with kt -> safe to alias as reduction buffer
  float* red = reinterpret_cast<float*>(kt);  // [16 waves][16 rows][5]
  if (lane < 16) {
    int base = (wave * 16 + rloc) * 5;
    red[base + 0] = denom;
    red[base + 1] = a0;
    red[base + 2] = a1;
    red[base + 3] = a2;
    red[base + 4] = a3;
  }
  __syncthreads();

  if (wave == 0) {
    const int grp = lane >> 4;  // 0..3
    float d = 0.f, b0 = 0.f, b1 = 0.f, b2 = 0.f, b3 = 0.f;
#pragma unroll
    for (int i = 0; i < 4; ++i) {
      const float* p = red + ((grp * 4 + i) * 16 + rloc) * 5;
      d += p[0];
      b0 += p[1];
      b1 += p[2];
      b2 += p[3];
      b3 += p[4];
    }
#pragma unroll
    for (int off = 16; off <= 32; off <<= 1) {
      d += __shfl_xor(d, off, 64);
      b0 += __shfl_xor(b0, off, 64);
      b1 += __shfl_xor(b1, off, 64);
      b2 += __shfl_xor(b2, off, 64);
      b3 += __shfl_xor(b3, off, 64);
    }
    if (lane < 16) {
      reinterpret_cast<float4*>(out)[row] =
          make_float4(b0 / d, b1 / d, b2 / d, b3 / d);
    }
  }
}

extern "C" void kernel_launch(void* const* d_in, const int* in_sizes, int n_in,
                              void* d_out, int out_size, void* d_ws, size_t ws_size,
                              hipStream_t stream) {
  const float* inp = (const float*)d_in[0];
  const float* rot = (const float*)d_in[1];
  const float* ent = (const float*)d_in[2];
  float* out = (float*)d_out;
  (void)d_ws; (void)ws_size;

  fused_attn_kernel<<<NROW / 16, 1024, 0, stream>>>(inp, rot, ent, out);
}

// Round 6
// 67.338 us; speedup vs baseline: 1.3935x; 1.0159x over previous
//
#include <hip/hip_runtime.h>

typedef float f2 __attribute__((ext_vector_type(2)));

#define NROW 4096
#define HJ   2048  // j-rows per LDS half

// Single fused kernel. 256 blocks x 1024 threads (16 waves); block owns 16 rows.
// Identity: cos((q-k)/2) = cos(q/2)cos(k/2) + sin(q/2)sin(k/2); sim in [0,1]
// => softmax needs no max pass. Block builds the k-side cos/sin table for all
// 4096 j's in LDS (two 2048-row halves, 64 KB), then accumulates.
// The softmax scale log2(e)/2 is pre-folded into the d=0 q-registers so the
// inner loop is 9 VALU slots + 1 v_exp per pair.
__global__ __launch_bounds__(1024) void fused_attn_kernel(
    const float* __restrict__ inp, const float* __restrict__ rot,
    const float* __restrict__ ent, float* __restrict__ out) {
  __shared__ float4 kt[2 * HJ];  // 64 KB; entry e = j*2+p: p0 = cos(k/2), p1 = sin(k/2)
  const int tid  = threadIdx.x;
  const int wave = tid >> 6;
  const int lane = tid & 63;
  const int rloc = lane & 15;
  const int row  = (blockIdx.x << 4) + rloc;
  const int g    = (wave << 2) + (lane >> 4);  // 0..63

  const float4* inp4 = reinterpret_cast<const float4*>(inp);

  // q-side for own row (registers)
  float4 xr = inp4[row];
  float qc[4], qs[4];
#pragma unroll
  for (int d = 0; d < 4; ++d) {
    float a = fmaf(xr.x, 0.5f * rot[d],
              fmaf(xr.y, 0.5f * rot[4 + d],
              fmaf(xr.z, 0.5f * rot[8 + d], xr.w * (0.5f * rot[12 + d]))));
    __sincosf(a, &qs[d], &qc[d]);
  }
  // fold softmax scale C = log2(e)/2 into the d=0 component: m comes out pre-scaled
  const float C = 0.72134752044448170367f;
  f2 qc01 = {qc[0] * C, qc[1]}, qc23 = {qc[2], qc[3]};
  f2 qs01 = {qs[0] * C, qs[1]}, qs23 = {qs[2], qs[3]};

  // hoisted scaled entangle params (SALU has no float mul; keep them in VGPRs)
  float se[16];
#pragma unroll
  for (int i = 0; i < 16; ++i) se[i] = 0.5f * ent[i];

  // piece parity: even tid writes cos-piece, odd writes sin-piece = cos(a - pi/2)
  const float phs = (tid & 1) ? -1.57079632679489662f : 0.f;

  float denom = 0.f;
  f2 a01 = {0.f, 0.f}, a23 = {0.f, 0.f};

  for (int h = 0; h < 2; ++h) {
    if (h) __syncthreads();  // all waves done reading kt half h-1
    // build half-table: thread t writes entries e = qq*1024 + t (16B lane stride
    // -> conflict-free ds_write_b128)
#pragma unroll
    for (int qq = 0; qq < 4; ++qq) {
      int e = qq * 1024 + tid;  // 0..4095
      int j = e >> 1;           // 0..2047 within half
      float4 xj = inp4[h * HJ + j];
      float4 val;
      val.x = __cosf(fmaf(xj.x, se[0],
                     fmaf(xj.y, se[4],
                     fmaf(xj.z, se[8],  fmaf(xj.w, se[12], phs)))));
      val.y = __cosf(fmaf(xj.x, se[1],
                     fmaf(xj.y, se[5],
                     fmaf(xj.z, se[9],  fmaf(xj.w, se[13], phs)))));
      val.z = __cosf(fmaf(xj.x, se[2],
                     fmaf(xj.y, se[6],
                     fmaf(xj.z, se[10], fmaf(xj.w, se[14], phs)))));
      val.w = __cosf(fmaf(xj.x, se[3],
                     fmaf(xj.y, se[7],
                     fmaf(xj.z, se[11], fmaf(xj.w, se[15], phs)))));
      kt[e] = val;
    }
    __syncthreads();

    // accumulate over this half's 2048 j's: 32 per lane.
    // group g reads kt entries spaced 32B -> wave covers 128B span, conflict-free
#pragma unroll 4
    for (int it = 0; it < 32; ++it) {
      int jj = (it << 6) + g;
      float4 c4 = kt[jj * 2];
      float4 s4 = kt[jj * 2 + 1];
      float4 v = inp4[h * HJ + jj];
      f2 c01 = {c4.x, c4.y}, c23 = {c4.z, c4.w};
      f2 s01 = {s4.x, s4.y}, s23 = {s4.z, s4.w};
      f2 t01 = c01 * qc01 + s01 * qs01;  // v_pk_mul + v_pk_fma
      f2 t23 = c23 * qc23 + s23 * qs23;
      f2 p = t01 * t23;                  // (C*t0*t2, t1*t3)
      float m = p.x * p.y;               // pre-scaled score
      float e = __builtin_amdgcn_exp2f(fabsf(m));  // abs is a free input modifier
      f2 e2 = {e, e};
      denom += e;
      a01 += e2 * (f2){v.x, v.y};
      a23 += e2 * (f2){v.z, v.w};
    }
  }

  float a0 = a01.x, a1 = a01.y, a2 = a23.x, a3 = a23.y;

  // in-wave reduce across the 4 slice-groups (lanes l, l^16, l^32, l^48)
#pragma unroll
  for (int off = 16; off <= 32; off <<= 1) {
    denom += __shfl_xor(denom, off, 64);
    a0 += __shfl_xor(a0, off, 64);
    a1 += __shfl_xor(a1, off, 64);
    a2 += __shfl_xor(a2, off, 64);
    a3 += __shfl_xor(a3, off, 64);
  }

  __syncthreads();  // everyone done with kt -> safe to alias as reduction buffer
  float* red = reinterpret_cast<float*>(kt);  // [16 waves][16 rows][5]
  if (lane < 16) {
    int base = (wave * 16 + rloc) * 5;
    red[base + 0] = denom;
    red[base + 1] = a0;
    red[base + 2] = a1;
    red[base + 3] = a2;
    red[base + 4] = a3;
  }
  __syncthreads();

  if (wave == 0) {
    const int grp = lane >> 4;  // 0..3
    float d = 0.f, b0 = 0.f, b1 = 0.f, b2 = 0.f, b3 = 0.f;
#pragma unroll
    for (int i = 0; i < 4; ++i) {
      const float* p = red + ((grp * 4 + i) * 16 + rloc) * 5;
      d += p[0];
      b0 += p[1];
      b1 += p[2];
      b2 += p[3];
      b3 += p[4];
    }
#pragma unroll
    for (int off = 16; off <= 32; off <<= 1) {
      d += __shfl_xor(d, off, 64);
      b0 += __shfl_xor(b0, off, 64);
      b1 += __shfl_xor(b1, off, 64);
      b2 += __shfl_xor(b2, off, 64);
      b3 += __shfl_xor(b3, off, 64);
    }
    if (lane < 16) {
      reinterpret_cast<float4*>(out)[row] =
          make_float4(b0 / d, b1 / d, b2 / d, b3 / d);
    }
  }
}

extern "C" void kernel_launch(void* const* d_in, const int* in_sizes, int n_in,
                              void* d_out, int out_size, void* d_ws, size_t ws_size,
                              hipStream_t stream) {
  const float* inp = (const float*)d_in[0];
  const float* rot = (const float*)d_in[1];
  const float* ent = (const float*)d_in[2];
  float* out = (float*)d_out;
  (void)d_ws; (void)ws_size;

  fused_attn_kernel<<<NROW / 16, 1024, 0, stream>>>(inp, rot, ent, out);
}